// Round 14
// baseline (115.679 us; speedup 1.0000x reference)
//
#include <hip/hip_runtime.h>
#include <hip/hip_bf16.h>
#include <cstdint>
#include <cmath>

#define DM 1024
#define NH 16
#define DK 64
#define NB 2
#define SS 2048
#define MM (NB*SS)   // 4096 rows

typedef unsigned short u16;
typedef uint32_t u32;
typedef __attribute__((ext_vector_type(4))) float f32x4;
typedef __attribute__((ext_vector_type(8))) short s16x8;
typedef __attribute__((ext_vector_type(2))) uint32_t u32x2;

__device__ __forceinline__ u16 f2bf(float f) {
    __hip_bfloat16 h = __float2bfloat16(f);
    return __builtin_bit_cast(u16, h);
}
__device__ __forceinline__ float bf2f(u16 u) {
    u32 x = (u32)u << 16;
    return __builtin_bit_cast(float, x);
}

// v_cvt_pk_bf16_f32: pack two f32 -> u32 of 2 bf16 (lo=first arg)
__device__ __forceinline__ u32 cvtpk(float a, float b) {
    u32 r;
    asm("v_cvt_pk_bf16_f32 %0, %1, %2" : "=v"(r) : "v"(a), "v"(b));
    return r;
}

__device__ __forceinline__ void gload_lds16(void* lds, const void* g) {
    __builtin_amdgcn_global_load_lds(
        (const __attribute__((address_space(1))) uint32_t*)g,
        (__attribute__((address_space(3))) uint32_t*)lds, 16, 0, 0);
}

// XOR-swizzled byte offset within a [rows][128B] LDS tile: 16B slot ^= row&7.
__device__ __forceinline__ int swz(int row, int cb) {
    return row * 128 + ((((cb) >> 4) ^ (row & 7)) << 4) + ((cb) & 15);
}

// ---------------- prep: cast x -> bf16 AND transpose-cast W (one launch) ----------------
__global__ void mha_prep(const float* __restrict__ x, u16* __restrict__ xb,
                         const float* __restrict__ W0, const float* __restrict__ W1,
                         const float* __restrict__ W2, const float* __restrict__ W3,
                         u16* __restrict__ WtBase) {
    const int bid = blockIdx.x, tid = threadIdx.x;
    if (bid < 4096) {
        int i = (bid * 256 + tid) * 4;
        float4 v = *reinterpret_cast<const float4*>(x + i);
        ushort4 o;
        o.x = f2bf(v.x); o.y = f2bf(v.y); o.z = f2bf(v.z); o.w = f2bf(v.w);
        *reinterpret_cast<ushort4*>(xb + i) = o;
        return;
    }
    __shared__ float t[32][33];
    const int b2 = bid - 4096;
    const int mat = b2 >> 10, rem = b2 & 1023;
    const int cx = rem & 31, cy = rem >> 5;
    const float* W = (mat == 0) ? W0 : (mat == 1) ? W1 : (mat == 2) ? W2 : W3;
    u16* Wt = WtBase + (size_t)mat * DM * DM;
    const int c0 = cx * 32, r0 = cy * 32;
    const int tx = tid & 31, ty = tid >> 5;
#pragma unroll
    for (int i = ty; i < 32; i += 8)
        t[i][tx] = W[(size_t)(r0 + i) * DM + c0 + tx];
    __syncthreads();
#pragma unroll
    for (int i = ty; i < 32; i += 8)
        Wt[(size_t)(c0 + i) * DM + r0 + tx] = f2bf(t[tx][i]);
}

// ---------------- 128x64 tile bf16 MFMA GEMM main loop ----------------
// 4 waves as 2x2; wave (wr,wc) owns 64x32. acc[4][2]. As 128x64 (16KB), Bs 64x64 (8KB).
__device__ __forceinline__ void gemm_loop64(const u16* __restrict__ A, const u16* __restrict__ Bt,
                                            int m0, int n0,
                                            u16 (*As)[64], u16 (*Bs)[64], f32x4 acc[4][2]) {
    const int tid = threadIdx.x;
    const int wave = tid >> 6, lane = tid & 63;
    const int lr = lane & 15, kg = lane >> 4;
    const int wr = wave >> 1, wc = wave & 1;

    for (int k0 = 0; k0 < DM; k0 += 64) {
        __syncthreads();
#pragma unroll
        for (int i = 0; i < 4; ++i) {
            const int o   = ((wave * 4 + i) * 64 + lane) * 16;
            const int row = o >> 7;
            const int kb  = o & 127;
            gload_lds16((char*)As + o, A + (size_t)(m0 + row) * DM + k0 + (kb >> 1));
        }
#pragma unroll
        for (int i = 0; i < 2; ++i) {
            const int o   = ((wave * 2 + i) * 64 + lane) * 16;
            const int row = o >> 7;
            const int kb  = o & 127;
            gload_lds16((char*)Bs + o, Bt + (size_t)(n0 + row) * DM + k0 + (kb >> 1));
        }
        __syncthreads();
#pragma unroll
        for (int kk = 0; kk < 64; kk += 32) {
            s16x8 a[4], b[2];
#pragma unroll
            for (int m = 0; m < 4; ++m)
                a[m] = *reinterpret_cast<const s16x8*>(&As[wr * 64 + m * 16 + lr][kk + kg * 8]);
#pragma unroll
            for (int n = 0; n < 2; ++n)
                b[n] = *reinterpret_cast<const s16x8*>(&Bs[wc * 32 + n * 16 + lr][kk + kg * 8]);
#pragma unroll
            for (int m = 0; m < 4; ++m)
#pragma unroll
                for (int n = 0; n < 2; ++n)
                    acc[m][n] = __builtin_amdgcn_mfma_f32_16x16x32_bf16(a[m], b[n], acc[m][n], 0, 0, 0);
        }
    }
}

// QKV GEMM, 128x64 tile: grid (32,16,3) = 1536 blocks -> 6 blocks/CU (24KB LDS),
// 6 waves/SIMD of independent barrier groups (r13 lesson: stall-bound, nothing
// saturated -> occupancy is the lever). LDS-image epilogue (2 K/V tiles or 128
// Q-rows of one head), coalesced 16B copy-out.
__global__ __launch_bounds__(256, 4) void mha_gemm_qkv(const u16* __restrict__ xb, const u16* __restrict__ Wt,
                                                       const float* __restrict__ bq, const float* __restrict__ bk,
                                                       const float* __restrict__ bv, u16* __restrict__ qkv) {
    __shared__ __align__(16) char smem[24576];
    u16 (*As)[64] = reinterpret_cast<u16(*)[64]>(smem);
    u16 (*Bs)[64] = reinterpret_cast<u16(*)[64]>(smem + 16384);

    const int m0 = blockIdx.x * 128;
    const int n0 = blockIdx.y * 64;
    const int z  = blockIdx.z;

    const float* bias = (z == 0) ? bq : (z == 1) ? bk : bv;
    const float scale = (z == 0) ? 0.125f * 1.44269504088896f : 1.0f;
    u16* Cout = qkv + (size_t)z * MM * DM;

    f32x4 acc[4][2] = {};
    gemm_loop64(xb, Wt + (size_t)z * DM * DM, m0, n0, As, Bs, acc);

    const int tid = threadIdx.x;
    const int wave = tid >> 6, lane = tid & 63;
    const int lr = lane & 15, kg = lane >> 4;
    const int wr = wave >> 1, wc = wave & 1;

    __syncthreads();   // all waves done reading As/Bs before image writes
    // ---- acc -> LDS image (16KB, bijective) ----
#pragma unroll
    for (int m = 0; m < 4; ++m)
#pragma unroll
        for (int n = 0; n < 2; ++n) {
            const int col = wc * 32 + n * 16 + lr;        // 0..63 (d within head)
            const float bv2 = bias[n0 + col];
#pragma unroll
            for (int j2 = 0; j2 < 4; ++j2) {
                const int row = wr * 64 + m * 16 + kg * 4 + j2;  // 0..127 (s-local)
                const float v = (acc[m][n][j2] + bv2) * scale;
                int imgoff;
                if (z == 0) {
                    imgoff = row * 128 + col * 2;
                } else if (z == 1) {
                    imgoff = (row >> 6) * 8192 + swz(row & 63, col * 2);
                } else {
                    imgoff = (row >> 6) * 8192 + swz(col, ((row & 63) >> 1) * 4 + (row & 1) * 2);
                }
                *reinterpret_cast<u16*>(smem + imgoff) = f2bf(v);
            }
        }
    __syncthreads();
    // ---- LDS -> global, coalesced 16B chunks (1024 chunks) ----
    const int bb = m0 >> 11, s0 = m0 & (SS - 1);
    const int kt0 = s0 >> 6, h0 = n0 >> 6;
#pragma unroll
    for (int it = 0; it < 4; ++it) {
        const int c = it * 256 + tid;     // 16B chunk id, 0..1023
        const s16x8 v = *reinterpret_cast<const s16x8*>(smem + c * 16);
        u16* dst;
        if (z == 0) {
            const int srow = c >> 3, d0 = (c & 7) * 8;
            dst = Cout + (((size_t)(bb * NH + h0) * SS + (s0 + srow)) * DK) + d0;
        } else {
            const int ktl = c >> 9, off = (c & 511) * 8;   // u16 units
            dst = Cout + ((size_t)(bb * NH + h0) * 32 + kt0 + ktl) * 4096 + off;
        }
        *reinterpret_cast<s16x8*>(dst) = v;
    }
}

__global__ __launch_bounds__(256, 4) void mha_gemm_out(const u16* __restrict__ AO, const u16* __restrict__ WoT,
                                                       const float* __restrict__ bo, float* __restrict__ out) {
    __shared__ __align__(16) char smem[24576];
    u16 (*As)[64] = reinterpret_cast<u16(*)[64]>(smem);
    u16 (*Bs)[64] = reinterpret_cast<u16(*)[64]>(smem + 16384);

    const int m0 = blockIdx.x * 128;
    const int n0 = blockIdx.y * 64;

    f32x4 acc[4][2] = {};
    gemm_loop64(AO, WoT, m0, n0, As, Bs, acc);

    const int tid = threadIdx.x;
    const int wave = tid >> 6, lane = tid & 63;
    const int lr = lane & 15, kg = lane >> 4;
    const int wr = wave >> 1, wc = wave & 1;
#pragma unroll
    for (int m = 0; m < 4; ++m)
#pragma unroll
        for (int n = 0; n < 2; ++n) {
            const int col = n0 + wc * 32 + n * 16 + lr;
            const float bv = bo[col];
#pragma unroll
            for (int j2 = 0; j2 < 4; ++j2) {
                const int row = m0 + wr * 64 + m * 16 + kg * 4 + j2;
                out[(size_t)row * DM + col] = acc[m][n][j2] + bv;
            }
        }
}

// ---------------- flash attention v10 (unchanged): DMA staging ----------------
__device__ const unsigned char JQT[48] = {
    15,31,30,31, 14,29,30,28,29, 13,27,28,26,27, 12,25,26,24,25,
    11,23,24,22,23, 10,21,22,20,21, 9,19,20,18,19, 8,17,18,16,17,
    7,16, 6,5,4,3,2,1,0};
__device__ const unsigned char JKS[48] = {
    0,0,15,16, 0,0,0,14,15, 0,0,0,13,14, 0,0,0,12,13,
    0,0,0,11,12, 0,0,0,10,11, 0,0,0,9,10, 0,0,0,8,9,
    0,0, 0,0,0,0,0,0,0};
__device__ const unsigned char JKL[48] = {
    16,16,16,16, 15,15,15,15,15, 14,14,14,14,14, 13,13,13,13,13,
    12,12,12,12,12, 11,11,11,11,11, 10,10,10,10,10, 9,9,9,9,9,
    8,8, 7,6,5,4,3,2,1};
__device__ const unsigned char JSL[48] = {
    255,30,29,31, 255,26,28,25,27, 255,22,24,21,23, 255,18,20,17,19,
    255,14,16,13,15, 255,10,12,9,11, 255,6,8,5,7, 255,2,4,1,3,
    255,0, 255,255,255,255,255,255,255};

__global__ __launch_bounds__(256, 4) void mha_attn(const u16* __restrict__ Qb, const u16* __restrict__ Kswz,
                                                   const u16* __restrict__ Vtswz, u16* __restrict__ AO,
                                                   u16* __restrict__ Opart, float* __restrict__ lpart) {
    // LDS: K dbuf 2x8KB @0 | V^T dbuf 2x8KB @16384 | Ps[4 waves][2KB] @32768
    __shared__ __align__(16) char lds[40960];

    const int bid = blockIdx.x;
    const int bh  = bid & 31;
    const int job = bid >> 5;
    const int qt   = JQT[job];
    const int kst  = JKS[job];
    const int klen = JKL[job];
    const int slot = JSL[job];
    const int qb = qt * 64;

    const int tid = threadIdx.x, w = tid >> 6, lane = tid & 63;
    const int lr = lane & 15, kg = lane >> 4;

    const u16* Qh = Qb + (size_t)bh * SS * DK;
    const char* Ktiles = (const char*)(Kswz  + (size_t)bh * 32 * 4096);
    const char* Vtiles = (const char*)(Vtswz + (size_t)bh * 32 * 4096);
    const int bb = bh >> 4, hh = bh & (NH - 1);
    char* psb = lds + 32768 + w * 2048;
    const int o = tid * 16;

    const int qrow = qb + w * 16 + lr;
    const s16x8 qf0 = *reinterpret_cast<const s16x8*>(Qh + (size_t)qrow * DK + kg * 8);
    const s16x8 qf1 = *reinterpret_cast<const s16x8*>(Qh + (size_t)qrow * DK + 32 + kg * 8);
    f32x4 accO[4] = {};
    float lp = 0.f;

    const int kend = kst + klen;
    {
        const char* Kt = Ktiles + kst * 8192;
        const char* Vt = Vtiles + kst * 8192;
        gload_lds16(lds + o,                 Kt + o);
        gload_lds16(lds + o + 4096,          Kt + o + 4096);
        gload_lds16(lds + 16384 + o,         Vt + o);
        gload_lds16(lds + 16384 + o + 4096,  Vt + o + 4096);
    }

    for (int t = kst; t < kend; ++t) {
        const int buf = (t - kst) & 1;
        asm volatile("s_waitcnt vmcnt(0)" ::: "memory");
        __syncthreads();
        if (t + 1 < kend) {
            const char* Kt = Ktiles + (t + 1) * 8192;
            const char* Vt = Vtiles + (t + 1) * 8192;
            char* kb2 = lds + (buf ^ 1) * 8192;
            char* vb2 = lds + 16384 + (buf ^ 1) * 8192;
            gload_lds16(kb2 + o,        Kt + o);
            gload_lds16(kb2 + o + 4096, Kt + o + 4096);
            gload_lds16(vb2 + o,        Vt + o);
            gload_lds16(vb2 + o + 4096, Vt + o + 4096);
        }
        const char* ksb = lds + buf * 8192;
        const char* vtb = lds + 16384 + buf * 8192;

        // swapped QK^T: lane holds P[q=lr][k=f*16+kg*4+j]
        f32x4 sc[4];
#pragma unroll
        for (int f = 0; f < 4; ++f) {
            s16x8 kf0 = *reinterpret_cast<const s16x8*>(ksb + swz(f * 16 + lr, kg * 16));
            s16x8 kf1 = *reinterpret_cast<const s16x8*>(ksb + swz(f * 16 + lr, 64 + kg * 16));
            f32x4 s = {};
            s = __builtin_amdgcn_mfma_f32_16x16x32_bf16(kf0, qf0, s, 0, 0, 0);
            s = __builtin_amdgcn_mfma_f32_16x16x32_bf16(kf1, qf1, s, 0, 0, 0);
            sc[f] = s;
        }
#pragma unroll
        for (int f = 0; f < 4; ++f)
#pragma unroll
            for (int j = 0; j < 4; ++j)
                sc[f][j] = __builtin_amdgcn_exp2f(sc[f][j]);
        if (t == qt) {
            const int qloc = w * 16 + lr;
#pragma unroll
            for (int f = 0; f < 4; ++f) {
                const int kc = f * 16 + kg * 4;
#pragma unroll
                for (int j = 0; j < 4; ++j)
                    if (kc + j > qloc) sc[f][j] = 0.f;
            }
        }
        float fs0 = 0.f, fs1 = 0.f;
#pragma unroll
        for (int f = 0; f < 4; ++f) {
            u32x2 pp;
            pp[0] = cvtpk(sc[f][0], sc[f][1]);
            pp[1] = cvtpk(sc[f][2], sc[f][3]);
            *reinterpret_cast<u32x2*>(psb + swz(lr, f * 32 + kg * 8)) = pp;
            const float s01 = sc[f][0] + sc[f][1], s23 = sc[f][2] + sc[f][3];
            if (f & 1) fs1 += s01 + s23; else fs0 += s01 + s23;
        }
        lp += fs0 + fs1;

        const s16x8 pf0 = *reinterpret_cast<const s16x8*>(psb + swz(lr, kg * 16));
        const s16x8 pf1 = *reinterpret_cast<const s16x8*>(psb + swz(lr, 64 + kg * 16));
#pragma unroll
        for (int db = 0; db < 4; ++db) {
            s16x8 vf0 = *reinterpret_cast<const s16x8*>(vtb + swz(db * 16 + lr, kg * 16));
            s16x8 vf1 = *reinterpret_cast<const s16x8*>(vtb + swz(db * 16 + lr, 64 + kg * 16));
            accO[db] = __builtin_amdgcn_mfma_f32_16x16x32_bf16(pf0, vf0, accO[db], 0, 0, 0);
            accO[db] = __builtin_amdgcn_mfma_f32_16x16x32_bf16(pf1, vf1, accO[db], 0, 0, 0);
        }
    }

    lp += __shfl_xor(lp, 16, 64);
    lp += __shfl_xor(lp, 32, 64);

    if (slot == 255) {
        float inv[4];
#pragma unroll
        for (int j = 0; j < 4; ++j)
            inv[j] = 1.0f / __shfl(lp, kg * 4 + j, 64);
#pragma unroll
        for (int db = 0; db < 4; ++db) {
            const int d = db * 16 + lr;
#pragma unroll
            for (int j = 0; j < 4; ++j) {
                const int s = qb + w * 16 + kg * 4 + j;
                AO[((size_t)(bb * SS + s)) * DM + hh * DK + d] = f2bf(accO[db][j] * inv[j]);
            }
        }
    } else {
        const int idx = bh * 32 + slot;
        u16* Od = Opart + (size_t)idx * 4096;
#pragma unroll
        for (int db = 0; db < 4; ++db) {
            const int d = db * 16 + lr;
#pragma unroll
            for (int j = 0; j < 4; ++j)
                Od[(w * 16 + kg * 4 + j) * 64 + d] = f2bf(accO[db][j]);
        }
        if (lane < 16)
            lpart[idx * 64 + w * 16 + lane] = lp;
    }
}

// combine partials for split q-tiles: AO = (O0+O1)/(l0+l1)
__global__ __launch_bounds__(256) void mha_combine(const u16* __restrict__ Opart,
                                                   const float* __restrict__ lpart,
                                                   u16* __restrict__ AO) {
    const int blk = blockIdx.x;          // 0..511
    const int bh = blk & 31, q = blk >> 5;
    const int qt = 16 + q;
    const int t = threadIdx.x;
    const int row = t >> 2, c0 = (t & 3) * 16;
    const int idx0 = bh * 32 + q * 2;
    const u16* O0 = Opart + (size_t)idx0 * 4096 + row * 64 + c0;
    const u16* O1 = O0 + 4096;
    const float l = lpart[idx0 * 64 + row] + lpart[(idx0 + 1) * 64 + row];
    const float inv = 1.0f / l;
    const int bb = bh >> 4, hh = bh & (NH - 1);
    const int s = qt * 64 + row;
    u16* dst = AO + ((size_t)(bb * SS + s)) * DM + hh * DK + c0;
#pragma unroll
    for (int h = 0; h < 2; ++h) {
        s16x8 a = *reinterpret_cast<const s16x8*>(O0 + h * 8);
        s16x8 b = *reinterpret_cast<const s16x8*>(O1 + h * 8);
        u16* ap = (u16*)&a; u16* bp = (u16*)&b;
        u16 ov[8];
#pragma unroll
        for (int i = 0; i < 8; ++i)
            ov[i] = f2bf((bf2f(ap[i]) + bf2f(bp[i])) * inv);
        *reinterpret_cast<ushort4*>(dst + h * 8) = *reinterpret_cast<ushort4*>(&ov[0]);
        *reinterpret_cast<ushort4*>(dst + h * 8 + 4) = *reinterpret_cast<ushort4*>(&ov[4]);
    }
}

extern "C" void kernel_launch(void* const* d_in, const int* in_sizes, int n_in,
                              void* d_out, int out_size, void* d_ws, size_t ws_size,
                              hipStream_t stream) {
    const float* x  = (const float*)d_in[0];
    const float* Wq = (const float*)d_in[2];
    const float* bq = (const float*)d_in[3];
    const float* Wk = (const float*)d_in[4];
    const float* bk = (const float*)d_in[5];
    const float* Wv = (const float*)d_in[6];
    const float* bv = (const float*)d_in[7];
    const float* Wo = (const float*)d_in[8];
    const float* bo = (const float*)d_in[9];
    float* out = (float*)d_out;

    char* ws = (char*)d_ws;
    u16* xb  = (u16*)(ws);                       // 8 MB (dead after gemm_qkv)
    u16* Wt  = (u16*)(ws + ((size_t)8  << 20));  // 8 MB (Wq,Wk,Wv dead after qkv; Wo^T kept)
    u16* qkv = (u16*)(ws + ((size_t)16 << 20));  // 24 MB: Q | K-swz tiles | V^T-swz tiles
    u16* AO  = (u16*)(ws + ((size_t)40 << 20));  // 8 MB
    // partial buffers overlap dead regions:
    u16*   Opart = (u16*)(ws);                       // 8 MB over xb
    float* lpart = (float*)(ws + ((size_t)8 << 20)); // 256 KB over Wq^T

    mha_prep<<<dim3(8192), dim3(256), 0, stream>>>(x, xb, Wq, Wk, Wv, Wo, Wt);
    mha_gemm_qkv<<<dim3(32, 16, 3), dim3(256), 0, stream>>>(xb, Wt, bq, bk, bv, qkv);
    mha_attn<<<dim3(1536), dim3(256), 0, stream>>>(qkv, qkv + (size_t)4194304, qkv + (size_t)8388608,
                                                   AO, Opart, lpart);
    mha_combine<<<dim3(512), dim3(256), 0, stream>>>(Opart, lpart, AO);
    mha_gemm_out<<<dim3(32, 16), dim3(256), 0, stream>>>(AO, Wt + (size_t)3 * DM * DM, bo, out);
}

// Round 15
// 107.275 us; speedup vs baseline: 1.0783x; 1.0783x over previous
//
#include <hip/hip_runtime.h>
#include <hip/hip_bf16.h>
#include <cstdint>
#include <cmath>

#define DM 1024
#define NH 16
#define DK 64
#define NB 2
#define SS 2048
#define MM (NB*SS)   // 4096 rows

typedef unsigned short u16;
typedef uint32_t u32;
typedef __attribute__((ext_vector_type(4))) float f32x4;
typedef __attribute__((ext_vector_type(8))) short s16x8;
typedef __attribute__((ext_vector_type(2))) uint32_t u32x2;

__device__ __forceinline__ u16 f2bf(float f) {
    __hip_bfloat16 h = __float2bfloat16(f);
    return __builtin_bit_cast(u16, h);
}
__device__ __forceinline__ float bf2f(u16 u) {
    u32 x = (u32)u << 16;
    return __builtin_bit_cast(float, x);
}

// v_cvt_pk_bf16_f32: pack two f32 -> u32 of 2 bf16 (lo=first arg)
__device__ __forceinline__ u32 cvtpk(float a, float b) {
    u32 r;
    asm("v_cvt_pk_bf16_f32 %0, %1, %2" : "=v"(r) : "v"(a), "v"(b));
    return r;
}

__device__ __forceinline__ void gload_lds16(void* lds, const void* g) {
    __builtin_amdgcn_global_load_lds(
        (const __attribute__((address_space(1))) uint32_t*)g,
        (__attribute__((address_space(3))) uint32_t*)lds, 16, 0, 0);
}

// XOR-swizzled byte offset within a [rows][128B] LDS tile: 16B slot ^= row&7.
__device__ __forceinline__ int swz(int row, int cb) {
    return row * 128 + ((((cb) >> 4) ^ (row & 7)) << 4) + ((cb) & 15);
}

// ---------------- prep: cast x -> bf16 AND transpose-cast W (one launch) ----------------
__global__ void mha_prep(const float* __restrict__ x, u16* __restrict__ xb,
                         const float* __restrict__ W0, const float* __restrict__ W1,
                         const float* __restrict__ W2, const float* __restrict__ W3,
                         u16* __restrict__ WtBase) {
    const int bid = blockIdx.x, tid = threadIdx.x;
    if (bid < 4096) {
        int i = (bid * 256 + tid) * 4;
        float4 v = *reinterpret_cast<const float4*>(x + i);
        ushort4 o;
        o.x = f2bf(v.x); o.y = f2bf(v.y); o.z = f2bf(v.z); o.w = f2bf(v.w);
        *reinterpret_cast<ushort4*>(xb + i) = o;
        return;
    }
    __shared__ float t[32][33];
    const int b2 = bid - 4096;
    const int mat = b2 >> 10, rem = b2 & 1023;
    const int cx = rem & 31, cy = rem >> 5;
    const float* W = (mat == 0) ? W0 : (mat == 1) ? W1 : (mat == 2) ? W2 : W3;
    u16* Wt = WtBase + (size_t)mat * DM * DM;
    const int c0 = cx * 32, r0 = cy * 32;
    const int tx = tid & 31, ty = tid >> 5;
#pragma unroll
    for (int i = ty; i < 32; i += 8)
        t[i][tx] = W[(size_t)(r0 + i) * DM + c0 + tx];
    __syncthreads();
#pragma unroll
    for (int i = ty; i < 32; i += 8)
        Wt[(size_t)(c0 + i) * DM + r0 + tx] = f2bf(t[tx][i]);
}

// ---------------- 128x128 tile GEMM loop, 2-phase counted-vmcnt double-buffer ----------------
// r14 diagnosis: the in-iter vmcnt(0) drain before the compute barrier is the
// structural stall (nothing >23% busy). T3/T4-minimum: stage tile t+1 into the
// other 32KB buffer BEFORE computing tile t; wait only vmcnt(8) (tile t's 8
// oldest loads, in-order retire per m135); raw s_barrier (no compiler drain);
// never vmcnt(0) mid-loop. sched_barrier(0) fences per rule #18.
__device__ __forceinline__ void gemm_loop_db(const u16* __restrict__ A, const u16* __restrict__ Bt,
                                             int m0, int n0, char* smem /*64KB*/, f32x4 acc[4][4]) {
    const int tid = threadIdx.x;
    const int wave = tid >> 6, lane = tid & 63;
    const int lr = lane & 15, kg = lane >> 4;
    const int wr = wave >> 1, wc = wave & 1;

    auto STAGE = [&](int buf, int k0) {
        char* As = smem + buf * 32768;
        char* Bs = As + 16384;
#pragma unroll
        for (int i = 0; i < 4; ++i) {
            const int o   = ((wave * 4 + i) * 64 + lane) * 16;
            const int row = o >> 7;
            const int kb  = o & 127;
            gload_lds16(As + o, A  + (size_t)(m0 + row) * DM + k0 + (kb >> 1));
            gload_lds16(Bs + o, Bt + (size_t)(n0 + row) * DM + k0 + (kb >> 1));
        }
    };

    STAGE(0, 0);
    for (int t = 0; t < 16; ++t) {
        if (t + 1 < 16) {
            STAGE((t + 1) & 1, (t + 1) * 64);
            asm volatile("s_waitcnt vmcnt(8)" ::: "memory");   // tile t's 8 oldest done
        } else {
            asm volatile("s_waitcnt vmcnt(0)" ::: "memory");
        }
        __builtin_amdgcn_sched_barrier(0);
        __builtin_amdgcn_s_barrier();          // all waves: tile t resident
        __builtin_amdgcn_sched_barrier(0);

        const u16 (*As)[64] = reinterpret_cast<const u16(*)[64]>(smem + (t & 1) * 32768);
        const u16 (*Bs)[64] = reinterpret_cast<const u16(*)[64]>(smem + (t & 1) * 32768 + 16384);
#pragma unroll
        for (int kk = 0; kk < 64; kk += 32) {
            s16x8 a[4], b[4];
#pragma unroll
            for (int m = 0; m < 4; ++m)
                a[m] = *reinterpret_cast<const s16x8*>(&As[wr * 64 + m * 16 + lr][kk + kg * 8]);
#pragma unroll
            for (int n = 0; n < 4; ++n)
                b[n] = *reinterpret_cast<const s16x8*>(&Bs[wc * 64 + n * 16 + lr][kk + kg * 8]);
#pragma unroll
            for (int m = 0; m < 4; ++m)
#pragma unroll
                for (int n = 0; n < 4; ++n)
                    acc[m][n] = __builtin_amdgcn_mfma_f32_16x16x32_bf16(a[m], b[n], acc[m][n], 0, 0, 0);
        }
        __builtin_amdgcn_sched_barrier(0);
        __builtin_amdgcn_s_barrier();          // reads of buf done before next overwrite
        __builtin_amdgcn_sched_barrier(0);
    }
}

// QKV GEMM (128x128, dbuf): grid (32,8,3). LDS-image epilogue (r12-verified).
__global__ __launch_bounds__(256, 2) void mha_gemm_qkv(const u16* __restrict__ xb, const u16* __restrict__ Wt,
                                                       const float* __restrict__ bq, const float* __restrict__ bk,
                                                       const float* __restrict__ bv, u16* __restrict__ qkv) {
    __shared__ __align__(16) char smem[65536];
    const int m0 = blockIdx.x * 128, n0 = blockIdx.y * 128;
    const int z = blockIdx.z;
    const float* bias = (z == 0) ? bq : (z == 1) ? bk : bv;
    const float scale = (z == 0) ? 0.125f * 1.44269504088896f : 1.0f;
    u16* Cout = qkv + (size_t)z * MM * DM;

    f32x4 acc[4][4] = {};
    gemm_loop_db(xb, Wt + (size_t)z * DM * DM, m0, n0, smem, acc);

    const int tid = threadIdx.x;
    const int wave = tid >> 6, lane = tid & 63;
    const int lr = lane & 15, kg = lane >> 4;
    const int wr = wave >> 1, wc = wave & 1;

    // ---- acc -> LDS image (32KB, bijective; loop's final barrier covers reads) ----
#pragma unroll
    for (int m = 0; m < 4; ++m)
#pragma unroll
        for (int n = 0; n < 4; ++n) {
            const int col = wc * 64 + n * 16 + lr;        // 0..127 within block
            const float bv2 = bias[n0 + col];
#pragma unroll
            for (int j2 = 0; j2 < 4; ++j2) {
                const int row = wr * 64 + m * 16 + kg * 4 + j2;  // 0..127
                const float v = (acc[m][n][j2] + bv2) * scale;
                int imgoff;
                if (z == 0) {
                    imgoff = row * 256 + (col >> 6) * 128 + (col & 63) * 2;
                } else if (z == 1) {
                    imgoff = ((row >> 6) * 2 + (col >> 6)) * 8192 + swz(row & 63, (col & 63) * 2);
                } else {
                    imgoff = ((row >> 6) * 2 + (col >> 6)) * 8192
                           + swz(col & 63, ((row & 63) >> 1) * 4 + (row & 1) * 2);
                }
                *reinterpret_cast<u16*>(smem + imgoff) = f2bf(v);
            }
        }
    __syncthreads();
    // ---- LDS -> global, coalesced 16B chunks ----
    const int bb = m0 >> 11, s0 = m0 & (SS - 1);
    const int kt0 = s0 >> 6, h0 = n0 >> 6;
#pragma unroll
    for (int it = 0; it < 8; ++it) {
        const int c = it * 256 + tid;     // 16B chunk id, 0..2047
        const s16x8 v = *reinterpret_cast<const s16x8*>(smem + c * 16);
        u16* dst;
        if (z == 0) {
            const int srow = c >> 4, inrow = c & 15;
            const int hl = inrow >> 3, d0 = (inrow & 7) * 8;
            dst = Cout + (((size_t)(bb * NH + h0 + hl) * SS + (s0 + srow)) * DK) + d0;
        } else {
            const int quad = c >> 9, off = (c & 511) * 8;   // u16 units
            const int ktl = quad >> 1, hl = quad & 1;
            dst = Cout + ((size_t)(bb * NH + h0 + hl) * 32 + kt0 + ktl) * 4096 + off;
        }
        *reinterpret_cast<s16x8*>(dst) = v;
    }
}

__global__ __launch_bounds__(256, 2) void mha_gemm_out(const u16* __restrict__ AO, const u16* __restrict__ WoT,
                                                       const float* __restrict__ bo, float* __restrict__ out) {
    __shared__ __align__(16) char smem[65536];
    const int m0 = blockIdx.x * 128, n0 = blockIdx.y * 128;

    f32x4 acc[4][4] = {};
    gemm_loop_db(AO, WoT, m0, n0, smem, acc);

    const int tid = threadIdx.x;
    const int wave = tid >> 6, lane = tid & 63;
    const int lr = lane & 15, kg = lane >> 4;
    const int wr = wave >> 1, wc = wave & 1;
#pragma unroll
    for (int m = 0; m < 4; ++m)
#pragma unroll
        for (int n = 0; n < 4; ++n) {
            const int col = n0 + wc * 64 + n * 16 + lr;
            const float bv = bo[col];
#pragma unroll
            for (int j2 = 0; j2 < 4; ++j2) {
                const int row = m0 + wr * 64 + m * 16 + kg * 4 + j2;
                out[(size_t)row * DM + col] = acc[m][n][j2] + bv;
            }
        }
}

// ---------------- flash attention v10 (unchanged): DMA staging ----------------
__device__ const unsigned char JQT[48] = {
    15,31,30,31, 14,29,30,28,29, 13,27,28,26,27, 12,25,26,24,25,
    11,23,24,22,23, 10,21,22,20,21, 9,19,20,18,19, 8,17,18,16,17,
    7,16, 6,5,4,3,2,1,0};
__device__ const unsigned char JKS[48] = {
    0,0,15,16, 0,0,0,14,15, 0,0,0,13,14, 0,0,0,12,13,
    0,0,0,11,12, 0,0,0,10,11, 0,0,0,9,10, 0,0,0,8,9,
    0,0, 0,0,0,0,0,0,0};
__device__ const unsigned char JKL[48] = {
    16,16,16,16, 15,15,15,15,15, 14,14,14,14,14, 13,13,13,13,13,
    12,12,12,12,12, 11,11,11,11,11, 10,10,10,10,10, 9,9,9,9,9,
    8,8, 7,6,5,4,3,2,1};
__device__ const unsigned char JSL[48] = {
    255,30,29,31, 255,26,28,25,27, 255,22,24,21,23, 255,18,20,17,19,
    255,14,16,13,15, 255,10,12,9,11, 255,6,8,5,7, 255,2,4,1,3,
    255,0, 255,255,255,255,255,255,255};

__global__ __launch_bounds__(256, 4) void mha_attn(const u16* __restrict__ Qb, const u16* __restrict__ Kswz,
                                                   const u16* __restrict__ Vtswz, u16* __restrict__ AO,
                                                   u16* __restrict__ Opart, float* __restrict__ lpart) {
    // LDS: K dbuf 2x8KB @0 | V^T dbuf 2x8KB @16384 | Ps[4 waves][2KB] @32768
    __shared__ __align__(16) char lds[40960];

    const int bid = blockIdx.x;
    const int bh  = bid & 31;
    const int job = bid >> 5;
    const int qt   = JQT[job];
    const int kst  = JKS[job];
    const int klen = JKL[job];
    const int slot = JSL[job];
    const int qb = qt * 64;

    const int tid = threadIdx.x, w = tid >> 6, lane = tid & 63;
    const int lr = lane & 15, kg = lane >> 4;

    const u16* Qh = Qb + (size_t)bh * SS * DK;
    const char* Ktiles = (const char*)(Kswz  + (size_t)bh * 32 * 4096);
    const char* Vtiles = (const char*)(Vtswz + (size_t)bh * 32 * 4096);
    const int bb = bh >> 4, hh = bh & (NH - 1);
    char* psb = lds + 32768 + w * 2048;
    const int o = tid * 16;

    const int qrow = qb + w * 16 + lr;
    const s16x8 qf0 = *reinterpret_cast<const s16x8*>(Qh + (size_t)qrow * DK + kg * 8);
    const s16x8 qf1 = *reinterpret_cast<const s16x8*>(Qh + (size_t)qrow * DK + 32 + kg * 8);
    f32x4 accO[4] = {};
    float lp = 0.f;

    const int kend = kst + klen;
    {
        const char* Kt = Ktiles + kst * 8192;
        const char* Vt = Vtiles + kst * 8192;
        gload_lds16(lds + o,                 Kt + o);
        gload_lds16(lds + o + 4096,          Kt + o + 4096);
        gload_lds16(lds + 16384 + o,         Vt + o);
        gload_lds16(lds + 16384 + o + 4096,  Vt + o + 4096);
    }

    for (int t = kst; t < kend; ++t) {
        const int buf = (t - kst) & 1;
        asm volatile("s_waitcnt vmcnt(0)" ::: "memory");
        __syncthreads();
        if (t + 1 < kend) {
            const char* Kt = Ktiles + (t + 1) * 8192;
            const char* Vt = Vtiles + (t + 1) * 8192;
            char* kb2 = lds + (buf ^ 1) * 8192;
            char* vb2 = lds + 16384 + (buf ^ 1) * 8192;
            gload_lds16(kb2 + o,        Kt + o);
            gload_lds16(kb2 + o + 4096, Kt + o + 4096);
            gload_lds16(vb2 + o,        Vt + o);
            gload_lds16(vb2 + o + 4096, Vt + o + 4096);
        }
        const char* ksb = lds + buf * 8192;
        const char* vtb = lds + 16384 + buf * 8192;

        // swapped QK^T: lane holds P[q=lr][k=f*16+kg*4+j]
        f32x4 sc[4];
#pragma unroll
        for (int f = 0; f < 4; ++f) {
            s16x8 kf0 = *reinterpret_cast<const s16x8*>(ksb + swz(f * 16 + lr, kg * 16));
            s16x8 kf1 = *reinterpret_cast<const s16x8*>(ksb + swz(f * 16 + lr, 64 + kg * 16));
            f32x4 s = {};
            s = __builtin_amdgcn_mfma_f32_16x16x32_bf16(kf0, qf0, s, 0, 0, 0);
            s = __builtin_amdgcn_mfma_f32_16x16x32_bf16(kf1, qf1, s, 0, 0, 0);
            sc[f] = s;
        }
#pragma unroll
        for (int f = 0; f < 4; ++f)
#pragma unroll
            for (int j = 0; j < 4; ++j)
                sc[f][j] = __builtin_amdgcn_exp2f(sc[f][j]);
        if (t == qt) {
            const int qloc = w * 16 + lr;
#pragma unroll
            for (int f = 0; f < 4; ++f) {
                const int kc = f * 16 + kg * 4;
#pragma unroll
                for (int j = 0; j < 4; ++j)
                    if (kc + j > qloc) sc[f][j] = 0.f;
            }
        }
        float fs0 = 0.f, fs1 = 0.f;
#pragma unroll
        for (int f = 0; f < 4; ++f) {
            u32x2 pp;
            pp[0] = cvtpk(sc[f][0], sc[f][1]);
            pp[1] = cvtpk(sc[f][2], sc[f][3]);
            *reinterpret_cast<u32x2*>(psb + swz(lr, f * 32 + kg * 8)) = pp;
            const float s01 = sc[f][0] + sc[f][1], s23 = sc[f][2] + sc[f][3];
            if (f & 1) fs1 += s01 + s23; else fs0 += s01 + s23;
        }
        lp += fs0 + fs1;

        const s16x8 pf0 = *reinterpret_cast<const s16x8*>(psb + swz(lr, kg * 16));
        const s16x8 pf1 = *reinterpret_cast<const s16x8*>(psb + swz(lr, 64 + kg * 16));
#pragma unroll
        for (int db = 0; db < 4; ++db) {
            s16x8 vf0 = *reinterpret_cast<const s16x8*>(vtb + swz(db * 16 + lr, kg * 16));
            s16x8 vf1 = *reinterpret_cast<const s16x8*>(vtb + swz(db * 16 + lr, 64 + kg * 16));
            accO[db] = __builtin_amdgcn_mfma_f32_16x16x32_bf16(pf0, vf0, accO[db], 0, 0, 0);
            accO[db] = __builtin_amdgcn_mfma_f32_16x16x32_bf16(pf1, vf1, accO[db], 0, 0, 0);
        }
    }

    lp += __shfl_xor(lp, 16, 64);
    lp += __shfl_xor(lp, 32, 64);

    if (slot == 255) {
        float inv[4];
#pragma unroll
        for (int j = 0; j < 4; ++j)
            inv[j] = 1.0f / __shfl(lp, kg * 4 + j, 64);
#pragma unroll
        for (int db = 0; db < 4; ++db) {
            const int d = db * 16 + lr;
#pragma unroll
            for (int j = 0; j < 4; ++j) {
                const int s = qb + w * 16 + kg * 4 + j;
                AO[((size_t)(bb * SS + s)) * DM + hh * DK + d] = f2bf(accO[db][j] * inv[j]);
            }
        }
    } else {
        const int idx = bh * 32 + slot;
        u16* Od = Opart + (size_t)idx * 4096;
#pragma unroll
        for (int db = 0; db < 4; ++db) {
            const int d = db * 16 + lr;
#pragma unroll
            for (int j = 0; j < 4; ++j)
                Od[(w * 16 + kg * 4 + j) * 64 + d] = f2bf(accO[db][j]);
        }
        if (lane < 16)
            lpart[idx * 64 + w * 16 + lane] = lp;
    }
}

// combine partials for split q-tiles: AO = (O0+O1)/(l0+l1)
__global__ __launch_bounds__(256) void mha_combine(const u16* __restrict__ Opart,
                                                   const float* __restrict__ lpart,
                                                   u16* __restrict__ AO) {
    const int blk = blockIdx.x;          // 0..511
    const int bh = blk & 31, q = blk >> 5;
    const int qt = 16 + q;
    const int t = threadIdx.x;
    const int row = t >> 2, c0 = (t & 3) * 16;
    const int idx0 = bh * 32 + q * 2;
    const u16* O0 = Opart + (size_t)idx0 * 4096 + row * 64 + c0;
    const u16* O1 = O0 + 4096;
    const float l = lpart[idx0 * 64 + row] + lpart[(idx0 + 1) * 64 + row];
    const float inv = 1.0f / l;
    const int bb = bh >> 4, hh = bh & (NH - 1);
    const int s = qt * 64 + row;
    u16* dst = AO + ((size_t)(bb * SS + s)) * DM + hh * DK + c0;
#pragma unroll
    for (int h = 0; h < 2; ++h) {
        s16x8 a = *reinterpret_cast<const s16x8*>(O0 + h * 8);
        s16x8 b = *reinterpret_cast<const s16x8*>(O1 + h * 8);
        u16* ap = (u16*)&a; u16* bp = (u16*)&b;
        u16 ov[8];
#pragma unroll
        for (int i = 0; i < 8; ++i)
            ov[i] = f2bf((bf2f(ap[i]) + bf2f(bp[i])) * inv);
        *reinterpret_cast<ushort4*>(dst + h * 8) = *reinterpret_cast<ushort4*>(&ov[0]);
        *reinterpret_cast<ushort4*>(dst + h * 8 + 4) = *reinterpret_cast<ushort4*>(&ov[4]);
    }
}

extern "C" void kernel_launch(void* const* d_in, const int* in_sizes, int n_in,
                              void* d_out, int out_size, void* d_ws, size_t ws_size,
                              hipStream_t stream) {
    const float* x  = (const float*)d_in[0];
    const float* Wq = (const float*)d_in[2];
    const float* bq = (const float*)d_in[3];
    const float* Wk = (const float*)d_in[4];
    const float* bk = (const float*)d_in[5];
    const float* Wv = (const float*)d_in[6];
    const float* bv = (const float*)d_in[7];
    const float* Wo = (const float*)d_in[8];
    const float* bo = (const float*)d_in[9];
    float* out = (float*)d_out;

    char* ws = (char*)d_ws;
    u16* xb  = (u16*)(ws);                       // 8 MB (dead after gemm_qkv)
    u16* Wt  = (u16*)(ws + ((size_t)8  << 20));  // 8 MB (Wq,Wk,Wv dead after qkv; Wo^T kept)
    u16* qkv = (u16*)(ws + ((size_t)16 << 20));  // 24 MB: Q | K-swz tiles | V^T-swz tiles
    u16* AO  = (u16*)(ws + ((size_t)40 << 20));  // 8 MB
    // partial buffers overlap dead regions:
    u16*   Opart = (u16*)(ws);                       // 8 MB over xb
    float* lpart = (float*)(ws + ((size_t)8 << 20)); // 256 KB over Wq^T

    mha_prep<<<dim3(8192), dim3(256), 0, stream>>>(x, xb, Wq, Wk, Wv, Wo, Wt);
    mha_gemm_qkv<<<dim3(32, 8, 3), dim3(256), 0, stream>>>(xb, Wt, bq, bk, bv, qkv);
    mha_attn<<<dim3(1536), dim3(256), 0, stream>>>(qkv, qkv + (size_t)4194304, qkv + (size_t)8388608,
                                                   AO, Opart, lpart);
    mha_combine<<<dim3(512), dim3(256), 0, stream>>>(Opart, lpart, AO);
    mha_gemm_out<<<dim3(32, 8), dim3(256), 0, stream>>>(AO, Wt + (size_t)3 * DM * DM, bo, out);
}